// Round 13
// baseline (413.673 us; speedup 1.0000x reference)
//
#include <hip/hip_runtime.h>
#include <hip/hip_bf16.h>
#include <math.h>

// Problem constants
#define S_LEN 2048
#define DIM   2048
#define H_N   16
#define NOPE  128
#define ROPE  64
#define VD    128
#define LORA  512
#define D_QK  576
#define SCALE_F 0.07216878364870323f   // 192^-0.5
#define EPS_F 1e-6f
#define KVF 640                        // padded kv row (f32 elems)
#define KVS 1280                       // padded kv row (shorts)

typedef short short8 __attribute__((ext_vector_type(8)));
typedef short short4v __attribute__((ext_vector_type(4)));
typedef float floatx4 __attribute__((ext_vector_type(4)));

static __device__ inline unsigned short f2bf_bits(float f) {
  union { __hip_bfloat16 h; unsigned short u; } cv;
  cv.h = __float2bfloat16(f);
  return cv.u;
}

static __device__ inline float bf2f(unsigned short b) {
  union { unsigned u; float f; } cv;
  cv.u = (unsigned)b << 16;
  return cv.f;
}

// global_load_lds: LDS destination must be WAVE-UNIFORM; lane's 16B lands at
// base + lane*16 automatically.
static __device__ inline void gload_lds16(const short* gptr, short* lds_base_uniform) {
  __builtin_amdgcn_global_load_lds(
      (const __attribute__((address_space(1))) void*)gptr,
      (__attribute__((address_space(3))) void*)lds_base_uniform, 16, 0, 0);
}

static __device__ inline void cast8(const float* __restrict__ src,
                                    short* __restrict__ dst, int i) {
  float4 a = ((const float4*)src)[2 * i];
  float4 b = ((const float4*)src)[2 * i + 1];
  uint4 o;
  o.x = (unsigned)f2bf_bits(a.x) | ((unsigned)f2bf_bits(a.y) << 16);
  o.y = (unsigned)f2bf_bits(a.z) | ((unsigned)f2bf_bits(a.w) << 16);
  o.z = (unsigned)f2bf_bits(b.x) | ((unsigned)f2bf_bits(b.y) << 16);
  o.w = (unsigned)f2bf_bits(b.z) | ((unsigned)f2bf_bits(b.w) << 16);
  ((uint4*)dst)[i] = o;
}

// ---------------------------------------------------------------------------
// One kernel for ALL input casts (depend only on kernel inputs):
// x->xb, wq->wcat[0:3072), wkv_a->wcat[3072:3648), zero wcat[3648:3712),
// wkv_b->wkvbb, wo->wob.  Replaces 6 dispatches.
// ---------------------------------------------------------------------------
#define CSEG0 524288              // x        2048x2048/8
#define CSEG1 (CSEG0 + 786432)    // wq       3072x2048/8
#define CSEG2 (CSEG1 + 147456)    // wkv_a    576x2048/8
#define CSEG3 (CSEG2 + 16384)     // zero     64x2048/8
#define CSEG4 (CSEG3 + 262144)    // wkv_b    4096x512/8
#define CSEG5 (CSEG4 + 524288)    // wo       2048x2048/8  -> total 2260992
__global__ __launch_bounds__(256) void cast_all(
    const float* __restrict__ x, const float* __restrict__ wq,
    const float* __restrict__ wkv_a, const float* __restrict__ wkv_b,
    const float* __restrict__ wo, short* __restrict__ xb,
    short* __restrict__ wcat, short* __restrict__ wkvbb,
    short* __restrict__ wob) {
  int i = blockIdx.x * 256 + threadIdx.x;
  if (i < CSEG0) {
    cast8(x, xb, i);
  } else if (i < CSEG1) {
    cast8(wq, wcat, i - CSEG0);
  } else if (i < CSEG2) {
    cast8(wkv_a, wcat + 3072 * 2048, i - CSEG1);
  } else if (i < CSEG3) {
    ((uint4*)(wcat + 3072 * 2048 + 576 * 2048))[i - CSEG2] = (uint4){0u, 0u, 0u, 0u};
  } else if (i < CSEG4) {
    cast8(wkv_b, wkvbb, i - CSEG3);
  } else if (i < CSEG5) {
    cast8(wo, wob, i - CSEG4);
  }
}

// ---------------------------------------------------------------------------
// wukT[h][c][d] = wkv_b[h*256 + d][c]  (f32 in, bf16 out), c<512, d<128
// ---------------------------------------------------------------------------
__global__ __launch_bounds__(256) void transpose_wuk(
    const float* __restrict__ wkvb, short* __restrict__ wukT) {
  __shared__ float tile[32][33];
  const int h = blockIdx.z, c0 = blockIdx.y * 32, d0 = blockIdx.x * 32;
  const int t = threadIdx.x;
  const int r = t >> 3, c4 = (t & 7) * 4;
  float4 v = *(const float4*)(wkvb + ((long)h * 256 + d0 + r) * 512 + c0 + c4);
  tile[r][c4 + 0] = v.x; tile[r][c4 + 1] = v.y;
  tile[r][c4 + 2] = v.z; tile[r][c4 + 3] = v.w;
  __syncthreads();
  uint2 o;
  o.x = (unsigned)f2bf_bits(tile[c4 + 0][r]) | ((unsigned)f2bf_bits(tile[c4 + 1][r]) << 16);
  o.y = (unsigned)f2bf_bits(tile[c4 + 2][r]) | ((unsigned)f2bf_bits(tile[c4 + 3][r]) << 16);
  *(uint2*)(wukT + ((long)h * 512 + c0 + r) * 128 + d0 + c4) = o;
}

// ---------------------------------------------------------------------------
// MT=64 bf16 MFMA NT GEMM (verified round 11): acc 2x4, half-height A tile.
// ---------------------------------------------------------------------------
__global__ __launch_bounds__(256) void gemm_bf16_nt_m64(
    const short* __restrict__ A, const short* __restrict__ B, void* __restrict__ Cv,
    int K, int lda, int ldb, int ldc, long aB, long bB, long cB, int bf16out) {
  A += (long)blockIdx.z * aB;
  B += (long)blockIdx.z * bB;
  const int m0 = blockIdx.y * 64, n0 = blockIdx.x * 128;
  __shared__ short As[2][64 * 32];
  __shared__ short Bs[2][128 * 32];
  const int tid = threadIdx.x, w = tid >> 6, lane = tid & 63;
  const int ln = lane & 15, g = lane >> 4;
  const int mw = (w & 1) * 32, nw = (w >> 1) * 64;
  floatx4 acc[2][4];
#pragma unroll
  for (int i = 0; i < 2; ++i)
#pragma unroll
    for (int j = 0; j < 4; ++j) acc[i][j] = (floatx4){0.f, 0.f, 0.f, 0.f};

#define GEMM_STAGE64(k0_, b_)                                                  \
  {                                                                            \
    {                                                                          \
      const int bc = w * 64;                                                   \
      const int c = bc + lane;                                                 \
      const int row = c >> 2, quar = c & 3;                                    \
      gload_lds16(A + (long)(m0 + row) * lda + (k0_) + quar * 8, As[b_] + bc * 8); \
    }                                                                          \
    _Pragma("unroll")                                                          \
    for (int i = 0; i < 2; ++i) {                                              \
      const int bc = (i * 4 + w) * 64;                                         \
      const int c = bc + lane;                                                 \
      const int row = c >> 2, quar = c & 3;                                    \
      gload_lds16(B + (long)(n0 + row) * ldb + (k0_) + quar * 8, Bs[b_] + bc * 8); \
    }                                                                          \
  }

  GEMM_STAGE64(0, 0);
  __syncthreads();
  const int nk = K >> 5;
  for (int kt = 0; kt < nk; ++kt) {
    const int cb = kt & 1;
    if (kt + 1 < nk) GEMM_STAGE64((kt + 1) << 5, cb ^ 1);
    short8 af[2], bf_[4];
#pragma unroll
    for (int mi = 0; mi < 2; ++mi)
      af[mi] = *(const short8*)(As[cb] + (mw + mi * 16 + ln) * 32 + g * 8);
#pragma unroll
    for (int ni = 0; ni < 4; ++ni)
      bf_[ni] = *(const short8*)(Bs[cb] + (nw + ni * 16 + ln) * 32 + g * 8);
#pragma unroll
    for (int mi = 0; mi < 2; ++mi)
#pragma unroll
      for (int ni = 0; ni < 4; ++ni)
        acc[mi][ni] = __builtin_amdgcn_mfma_f32_16x16x32_bf16(af[mi], bf_[ni], acc[mi][ni], 0, 0, 0);
    __syncthreads();
  }
#undef GEMM_STAGE64
  if (bf16out) {
    short* Cs = (short*)Cv + (long)blockIdx.z * cB;
#pragma unroll
    for (int mi = 0; mi < 2; ++mi)
#pragma unroll
      for (int ni = 0; ni < 4; ++ni)
#pragma unroll
        for (int r = 0; r < 4; ++r)
          Cs[(long)(m0 + mw + mi * 16 + g * 4 + r) * ldc + n0 + nw + ni * 16 + ln] =
              (short)f2bf_bits(acc[mi][ni][r]);
  } else {
    float* C = (float*)Cv + (long)blockIdx.z * cB;
#pragma unroll
    for (int mi = 0; mi < 2; ++mi)
#pragma unroll
      for (int ni = 0; ni < 4; ++ni)
#pragma unroll
        for (int r = 0; r < 4; ++r)
          C[(long)(m0 + mw + mi * 16 + g * 4 + r) * ldc + n0 + nw + ni * 16 + ln] = acc[mi][ni][r];
  }
}

// ---------------------------------------------------------------------------
// Merged step-2/3 GEMM (verified r12): B = wcat [3712][2048] = [wq;wkv_a;0].
// n0<3072 -> bf16 qbuf (ldc 3072); n0>=3072 -> f32 kvpad (ldc KVF).
// ---------------------------------------------------------------------------
__global__ __launch_bounds__(256) void gemm_qkv_m64(
    const short* __restrict__ A, const short* __restrict__ B,
    short* __restrict__ Cq, float* __restrict__ Ckv) {
  const int m0 = blockIdx.y * 64, n0 = blockIdx.x * 128;
  __shared__ short As[2][64 * 32];
  __shared__ short Bs[2][128 * 32];
  const int tid = threadIdx.x, w = tid >> 6, lane = tid & 63;
  const int ln = lane & 15, g = lane >> 4;
  const int mw = (w & 1) * 32, nw = (w >> 1) * 64;
  floatx4 acc[2][4];
#pragma unroll
  for (int i = 0; i < 2; ++i)
#pragma unroll
    for (int j = 0; j < 4; ++j) acc[i][j] = (floatx4){0.f, 0.f, 0.f, 0.f};

#define QKV_STAGE(k0_, b_)                                                     \
  {                                                                            \
    {                                                                          \
      const int bc = w * 64;                                                   \
      const int c = bc + lane;                                                 \
      const int row = c >> 2, quar = c & 3;                                    \
      gload_lds16(A + (long)(m0 + row) * 2048 + (k0_) + quar * 8, As[b_] + bc * 8); \
    }                                                                          \
    _Pragma("unroll")                                                          \
    for (int i = 0; i < 2; ++i) {                                              \
      const int bc = (i * 4 + w) * 64;                                         \
      const int c = bc + lane;                                                 \
      const int row = c >> 2, quar = c & 3;                                    \
      gload_lds16(B + (long)(n0 + row) * 2048 + (k0_) + quar * 8, Bs[b_] + bc * 8); \
    }                                                                          \
  }

  QKV_STAGE(0, 0);
  __syncthreads();
  for (int kt = 0; kt < 64; ++kt) {
    const int cb = kt & 1;
    if (kt + 1 < 64) QKV_STAGE((kt + 1) << 5, cb ^ 1);
    short8 af[2], bf_[4];
#pragma unroll
    for (int mi = 0; mi < 2; ++mi)
      af[mi] = *(const short8*)(As[cb] + (mw + mi * 16 + ln) * 32 + g * 8);
#pragma unroll
    for (int ni = 0; ni < 4; ++ni)
      bf_[ni] = *(const short8*)(Bs[cb] + (nw + ni * 16 + ln) * 32 + g * 8);
#pragma unroll
    for (int mi = 0; mi < 2; ++mi)
#pragma unroll
      for (int ni = 0; ni < 4; ++ni)
        acc[mi][ni] = __builtin_amdgcn_mfma_f32_16x16x32_bf16(af[mi], bf_[ni], acc[mi][ni], 0, 0, 0);
    __syncthreads();
  }
#undef QKV_STAGE
  if (n0 < 3072) {
#pragma unroll
    for (int mi = 0; mi < 2; ++mi)
#pragma unroll
      for (int ni = 0; ni < 4; ++ni)
#pragma unroll
        for (int r = 0; r < 4; ++r)
          Cq[(long)(m0 + mw + mi * 16 + g * 4 + r) * 3072 + n0 + nw + ni * 16 + ln] =
              (short)f2bf_bits(acc[mi][ni][r]);
  } else {
#pragma unroll
    for (int mi = 0; mi < 2; ++mi)
#pragma unroll
      for (int ni = 0; ni < 4; ++ni)
#pragma unroll
        for (int r = 0; r < 4; ++r)
          Ckv[(long)(m0 + mw + mi * 16 + g * 4 + r) * KVF + (n0 - 3072) + nw + ni * 16 + ln] =
              acc[mi][ni][r];
  }
}

// ---------------------------------------------------------------------------
// prep: RMSNorm + RoPE on kv rows (f32 stride KVF) -> bf16 in place (short
// stride KVS, first 576 valid); q_pe RoPE from bf16 qbufb -> bf16 qhat tail
// ---------------------------------------------------------------------------
__global__ __launch_bounds__(64) void prep_kernel(
    float* kv, const short* __restrict__ qbufb, short* __restrict__ qhatb,
    const float* __restrict__ cosp, const float* __restrict__ sinp,
    const float* __restrict__ normw) {
  const int s = blockIdx.x;
  const int l = threadIdx.x;
  float* row = kv + (long)s * KVF;
  short* krow = (short*)kv + (long)s * KVS;

  float4 v0 = *(const float4*)(row + l * 8);
  float4 v1 = *(const float4*)(row + l * 8 + 4);
  float rx0 = 0.f, rx1 = 0.f, rc = 0.f, rs = 0.f;
  if (l < 32) {
    rc = cosp[s * 32 + l];
    rs = sinp[s * 32 + l];
    rx0 = row[512 + 2 * l];
    rx1 = row[512 + 2 * l + 1];
  }
  float4 w0 = *(const float4*)(normw + l * 8);
  float4 w1 = *(const float4*)(normw + l * 8 + 4);

  float ss = v0.x * v0.x + v0.y * v0.y + v0.z * v0.z + v0.w * v0.w +
             v1.x * v1.x + v1.y * v1.y + v1.z * v1.z + v1.w * v1.w;
#pragma unroll
  for (int off = 32; off; off >>= 1) ss += __shfl_xor(ss, off, 64);
  const float scale = rsqrtf(ss * (1.0f / (float)LORA) + EPS_F);
  v0.x *= scale * w0.x; v0.y *= scale * w0.y; v0.z *= scale * w0.z; v0.w *= scale * w0.w;
  v1.x *= scale * w1.x; v1.y *= scale * w1.y; v1.z *= scale * w1.z; v1.w *= scale * w1.w;

  uint4 pk;
  pk.x = (unsigned)f2bf_bits(v0.x) | ((unsigned)f2bf_bits(v0.y) << 16);
  pk.y = (unsigned)f2bf_bits(v0.z) | ((unsigned)f2bf_bits(v0.w) << 16);
  pk.z = (unsigned)f2bf_bits(v1.x) | ((unsigned)f2bf_bits(v1.y) << 16);
  pk.w = (unsigned)f2bf_bits(v1.z) | ((unsigned)f2bf_bits(v1.w) << 16);
  *(uint4*)(krow + l * 8) = pk;

  if (l < 32) {
    const float y0 = rx0 * rc - rx1 * rs;
    const float y1 = rx0 * rs + rx1 * rc;
    unsigned pr = (unsigned)f2bf_bits(y0) | ((unsigned)f2bf_bits(y1) << 16);
    *(unsigned*)(krow + 512 + 2 * l) = pr;
  }

#pragma unroll
  for (int it = 0; it < 8; ++it) {
    const int p = it * 64 + l;
    const int h = p >> 5;
    const int i = p & 31;
    const float c = cosp[s * 32 + i];
    const float sn = sinp[s * 32 + i];
    const short* qp = qbufb + (long)s * 3072 + h * 192 + NOPE;
    const unsigned uq = *(const unsigned*)(qp + 2 * i);
    const float x0 = bf2f((unsigned short)uq);
    const float x1 = bf2f((unsigned short)(uq >> 16));
    const float y0 = x0 * c - x1 * sn;
    const float y1 = x0 * sn + x1 * c;
    short* dst = qhatb + ((long)h * S_LEN + s) * D_QK + 512;
    *(unsigned*)(dst + 2 * i) = (unsigned)f2bf_bits(y0) | ((unsigned)f2bf_bits(y1) << 16);
  }
}

// ---------------------------------------------------------------------------
// Transpose V: kvt[d][s] = kbf[s][d], d<512. kbf rows stride KVS shorts.
// ---------------------------------------------------------------------------
__global__ __launch_bounds__(256) void transpose_v(
    const short* __restrict__ kbf, short* __restrict__ kvt) {
  __shared__ short tile[32][36];
  const int d0 = blockIdx.x * 32;
  const int s0 = blockIdx.y * 32;
  const int t = threadIdx.x;
  const int r = t >> 3;
  const int c4 = (t & 7) * 4;
  uint2 v = *(const uint2*)(kbf + (long)(s0 + r) * KVS + d0 + c4);
  *(uint2*)(&tile[r][c4]) = v;
  __syncthreads();
  uint2 o;
  o.x = (unsigned)(unsigned short)tile[c4 + 0][r] | ((unsigned)(unsigned short)tile[c4 + 1][r] << 16);
  o.y = (unsigned)(unsigned short)tile[c4 + 2][r] | ((unsigned)(unsigned short)tile[c4 + 3][r] << 16);
  *(uint2*)(kvt + (long)(d0 + r) * S_LEN + s0 + c4) = o;
}

// ---------------------------------------------------------------------------
// Fragment-major K: ktt[kt][c][lane][8]
// ---------------------------------------------------------------------------
__global__ __launch_bounds__(256) void build_ktt(
    const short* __restrict__ kbf, short* __restrict__ ktt) {
  const int kt = blockIdx.x;                     // 0..127
  for (int idx = threadIdx.x; idx < 18 * 64; idx += 256) {
    const int c = idx >> 6, l = idx & 63;
    const int ln = l & 15, g = l >> 4;
    uint4 v = *(const uint4*)(kbf + (long)(kt * 16 + ln) * KVS + c * 32 + g * 8);
    *(uint4*)(ktt + ((long)(kt * 18 + c) * 64 + l) * 8) = v;
  }
}

// ---------------------------------------------------------------------------
// Fragment-major V^T: vtt[kt][nt][lane][8]
// ---------------------------------------------------------------------------
__global__ __launch_bounds__(256) void build_vtt(
    const short* __restrict__ kvt, short* __restrict__ vtt) {
  const int kt = blockIdx.x;                     // 0..63
  for (int idx = threadIdx.x; idx < 32 * 64; idx += 256) {
    const int nt = idx >> 6, l = idx & 63;
    const int ln = l & 15, g = l >> 4;
    uint4 v = *(const uint4*)(kvt + (long)(nt * 16 + ln) * S_LEN + kt * 32 + g * 8);
    *(uint4*)(vtt + ((long)(kt * 32 + nt) * 64 + l) * 8) = v;
  }
}

// ---------------------------------------------------------------------------
// Flash v14: v13 main loop (verified 160-163 us) + FUSED step-10 epilogue.
// After the KV loop, normalized bf16 O is written to LDS (reusing the dead
// Kt buffer, rows padded to 520 shorts to break bank conflicts), then each
// wave computes its out^T tile [64 d_out x 16 q] = w_uv @ O^T with K=512
// (64 MFMAs; A-frags streamed from L2-resident wkvbb, B-frags from LDS) and
// writes oprojb directly. Numerically identical to the separate step-10
// GEMM (same bf16 roundings, f32 accum). Saves the 33.5MB obuf write +
// 33.5MB read + one dispatch; short blocks run epilogue inside the drain
// tail of long blocks.
// ---------------------------------------------------------------------------
__global__ __launch_bounds__(512, 2) void flash_reg(
    const short* __restrict__ qhat,   // [H][S][576] bf16
    const short* __restrict__ ktt,    // [128][18][64][8] bf16 frag-major K
    const short* __restrict__ vtt,    // [64][32][64][8] bf16 frag-major V^T
    const short* __restrict__ wuv,    // wkvbb [4096][512] bf16 (w_uv at +128)
    short* __restrict__ oproj) {      // [S][2048] bf16
  const int bid = blockIdx.x;         // 0..511
  const int hp = bid & 7;             // head pair
  const int v = bid >> 3;             // 0..63
  const int vi = v & 31, vj = v >> 5;
  const int qt2 = (vj == 0) ? 63 - vi : vi;   // 32-query tile, longest first
  const int q0 = qt2 * 32;
  const int tid = threadIdx.x;
  const int w = tid >> 6;             // wave 0..7
  const int lane = tid & 63;
  const int ln = lane & 15, g = lane >> 4;
  const int hh = w & 1;               // head parity
  const int dh = (w >> 1) & 1;        // key-half for QK; d-half for PV
  const int qt = w >> 2;              // q-subtile (16 queries)
  const int h = hp * 2 + hh;
  const int qrow = q0 + qt * 16 + ln;
  const int qlim = qrow;

  __shared__ short Kt[2][36 * 512];              // 72 KB K pairs (dbuf)
  __shared__ short Vt[2][32 * 512];              // 64 KB V pairs (dbuf)
  __shared__ __align__(16) short Pl[2][2][2][16][40]; // [par][hh][qt][q][keypad]
  __shared__ float Ls[8][16];                    // cross-dh lsum exchange

  // Q B-frags: n = ln (query), k = g*8+j
  short8 qfr[18];
  {
    const short* qr = qhat + ((long)h * S_LEN + qrow) * D_QK;
#pragma unroll
    for (int c = 0; c < 18; ++c)
      qfr[c] = *(const short8*)(qr + c * 32 + g * 8);
  }

  floatx4 oacc[16];
#pragma unroll
  for (int nt = 0; nt < 16; ++nt) oacc[nt] = (floatx4){0.f, 0.f, 0.f, 0.f};
  float lsum = 0.f;

  const int npairs = qt2 + 1;         // 32-key steps

#define FL_STAGEK(pair_, b_)                                                   \
  {                                                                            \
    const short* ks_ = ktt + (long)(pair_) * (36 * 512);                       \
    _Pragma("unroll")                                                          \
    for (int i = 0; i < 5; ++i) {                                              \
      const int grp = i * 8 + w;                                               \
      if (grp < 36)                                                            \
        gload_lds16(ks_ + (long)(grp * 64 + lane) * 8, Kt[b_] + grp * 512);    \
    }                                                                          \
  }

#define FL_STAGEV(pair_, b_)                                                   \
  {                                                                            \
    const short* vs_ = vtt + (long)(pair_) * (32 * 512);                       \
    _Pragma("unroll")                                                          \
    for (int i = 0; i < 4; ++i) {                                              \
      const int grp = i * 8 + w;                                               \
      gload_lds16(vs_ + (long)(grp * 64 + lane) * 8, Vt[b_] + grp * 512);      \
    }                                                                          \
  }

#define FL_PV(par_)                                                            \
  {                                                                            \
    const short8 pb8 = *(const short8*)(&Pl[par_][hh][qt][ln][g * 8]);         \
    const short* vb_ = Vt[par_] + dh * (16 * 512);                             \
    _Pragma("unroll")                                                          \
    for (int half = 0; half < 2; ++half) {                                     \
      short8 va[8];                                                            \
      _Pragma("unroll")                                                        \
      for (int j = 0; j < 8; ++j)                                              \
        va[j] = *(const short8*)(vb_ + (half * 8 + j) * 512 + lane * 8);       \
      __builtin_amdgcn_s_setprio(1);                                           \
      _Pragma("unroll")                                                        \
      for (int j = 0; j < 8; ++j)                                              \
        oacc[half * 8 + j] = __builtin_amdgcn_mfma_f32_16x16x32_bf16(          \
            va[j], pb8, oacc[half * 8 + j], 0, 0, 0);                          \
      __builtin_amdgcn_s_setprio(0);                                           \
    }                                                                          \
  }

  FL_STAGEK(0, 0);
  __syncthreads();

  for (int p = 0; p < npairs; ++p) {
    const int cb = p & 1;
    if (p + 1 < npairs) FL_STAGEK(p + 1, cb ^ 1);
    FL_STAGEV(p, cb);
    // ---- QK^T on this wave's 16-key half (dh selects half of pair p) ----
    const short* kb = Kt[cb] + dh * (18 * 512);
    floatx4 s0 = (floatx4){0.f, 0.f, 0.f, 0.f};
    floatx4 s1 = (floatx4){0.f, 0.f, 0.f, 0.f};
    __builtin_amdgcn_s_setprio(1);
#pragma unroll
    for (int c = 0; c < 18; c += 2) {
      short8 k0 = *(const short8*)(kb + (c * 64 + lane) * 8);
      short8 k1 = *(const short8*)(kb + ((c + 1) * 64 + lane) * 8);
      s0 = __builtin_amdgcn_mfma_f32_16x16x32_bf16(k0, qfr[c], s0, 0, 0, 0);
      s1 = __builtin_amdgcn_mfma_f32_16x16x32_bf16(k1, qfr[c + 1], s1, 0, 0, 0);
    }
    __builtin_amdgcn_s_setprio(0);
    // ---- softmax on 4 scores: keys p*32 + dh*16 + 4g + r ----
    short4v p4;
    float psum = 0.f;
#pragma unroll
    for (int r = 0; r < 4; ++r) {
      const int ki = p * 32 + dh * 16 + g * 4 + r;
      float sc = fminf(fmaxf((s0[r] + s1[r]) * SCALE_F, -30.f), 30.f);
      float pv_ = (ki <= qlim) ? __expf(sc) : 0.f;
      psum += pv_;
      p4[r] = (short)f2bf_bits(pv_);
    }
    lsum += psum;
    // ---- publish P half-tile ----
    union { short4v s; unsigned long long u; } upk;
    upk.s = p4;
    *(unsigned long long*)(&Pl[cb][hh][qt][ln][dh * 16 + g * 4]) = upk.u;
    // ---- PV for pair p-1 (P and V both at parity cb^1, fenced) ----
    if (p > 0) FL_PV(cb ^ 1);
    __syncthreads();
  }
  // final pending PV (parity of last iteration)
  FL_PV((npairs - 1) & 1);
#undef FL_PV
#undef FL_STAGEV
#undef FL_STAGEK

  // denominator: reduce over g within wave, then across the dh pair (w^2)
  lsum += __shfl_xor(lsum, 16, 64);
  lsum += __shfl_xor(lsum, 32, 64);
  if (g == 0) Ls[w][ln] = lsum;
  __syncthreads();
  lsum += Ls[w ^ 2][ln];
  const float inv = 1.0f / fmaxf(lsum, 1e-30f);

  // ---- write normalized bf16 O to LDS (reuse Kt; all Kt reads done) ----
  // Ob layout: [hh][q 32][c 520pad] shorts; rows 1040B -> bank offset +4/row.
  short* Ob = &Kt[0][0];
  {
    short* obr = Ob + ((hh * 32 + qt * 16 + ln) * 520) + dh * 256 + g * 4;
#pragma unroll
    for (int nt = 0; nt < 16; ++nt) {
      unsigned lo = (unsigned)f2bf_bits(oacc[nt][0] * inv) | ((unsigned)f2bf_bits(oacc[nt][1] * inv) << 16);
      unsigned hi = (unsigned)f2bf_bits(oacc[nt][2] * inv) | ((unsigned)f2bf_bits(oacc[nt][3] * inv) << 16);
      unsigned long long st = (unsigned long long)lo | ((unsigned long long)hi << 32);
      *(unsigned long long*)(obr + nt * 16) = st;
    }
  }
  __syncthreads();

  // ---- fused oproj GEMM: out^T[d_out, q] = sum_c w_uv[d_out, c] O^T[c, q]
  // wave (hh,dh,qt): d_out in dh*64..+63, q in qt*16..+15, K = 512.
  {
    const short* wuvb = wuv + ((long)(h * 256 + 128 + dh * 64)) * 512;
    const short* obq = Ob + (hh * 32 + qt * 16 + ln) * 520;
    floatx4 pacc[4];
#pragma unroll
    for (int dt = 0; dt < 4; ++dt) pacc[dt] = (floatx4){0.f, 0.f, 0.f, 0.f};
#pragma unroll 4
    for (int ks = 0; ks < 16; ++ks) {
      short8 bfr = *(const short8*)(obq + ks * 32 + g * 8);
#pragma unroll
      for (int dt = 0; dt < 4; ++dt) {
        short8 afr = *(const short8*)(wuvb + ((long)(dt * 16 + ln)) * 512 + ks * 32 + g * 8);
        pacc[dt] = __builtin_amdgcn_mfma_f32_16x16x32_bf16(afr, bfr, pacc[dt], 0, 0, 0);
      }
    }
    // store: row d_out = dh*64+dt*16+g*4+r, col q = ln -> oproj[q][h*128+d]
    short* orow = oproj + ((long)qrow) * 2048 + h * 128 + dh * 64 + g * 4;
#pragma unroll
    for (int dt = 0; dt < 4; ++dt) {
      unsigned lo = (unsigned)f2bf_bits(pacc[dt][0]) | ((unsigned)f2bf_bits(pacc[dt][1]) << 16);
      unsigned hi = (unsigned)f2bf_bits(pacc[dt][2]) | ((unsigned)f2bf_bits(pacc[dt][3]) << 16);
      unsigned long long st = (unsigned long long)lo | ((unsigned long long)hi << 32);
      *(unsigned long long*)(orow + dt * 16) = st;
    }
  }
}

// ---------------------------------------------------------------------------
// Host launch
// ---------------------------------------------------------------------------
extern "C" void kernel_launch(void* const* d_in, const int* in_sizes, int n_in,
                              void* d_out, int out_size, void* d_ws, size_t ws_size,
                              hipStream_t stream) {
  (void)in_sizes; (void)n_in; (void)out_size; (void)ws_size;
  const float* x      = (const float*)d_in[0];
  const float* cosp   = (const float*)d_in[1];
  const float* sinp   = (const float*)d_in[2];
  const float* wq     = (const float*)d_in[3];
  const float* wkv_a  = (const float*)d_in[4];
  const float* normw  = (const float*)d_in[5];
  const float* wkv_b  = (const float*)d_in[6];
  const float* wo     = (const float*)d_in[7];
  float* out = (float*)d_out;

  float* ws = (float*)d_ws;
  float* qbufR  = ws;                                  // region A: 25.2 MB
  float* kvold  = qbufR + (long)S_LEN * 3072;          // 4.7 MB (spare)
  float* qhatR  = kvold + (long)S_LEN * D_QK;          // region B: 75.5 MB
  float* obufR  = qhatR + (long)H_N * S_LEN * D_QK;    // region C: 67 MB
  float* oprojR = obufR + (long)H_N * S_LEN * LORA;    // region D: 16.8 MB

  // region D: padded kv [S, KVF] f32 -> bf16 in place
  float* kvpad = oprojR;
  short* kbf = (short*)kvpad;                          // bf16 rows stride KVS

  // region A aliases
  short* qbufb = (short*)qbufR;                        // [S,3072] bf16 (12.6 MB)
  short* kvt = qbufb + (long)S_LEN * 3072;             // [512][S] bf16, 2 MB
  short* ktt = kvt + (long)512 * S_LEN;                // 2.36 MB frag-major K
  short* vtt = ktt + (long)128 * 18 * 64 * 8;          // 2 MB frag-major V^T

  // region B aliases
  short* qhatb  = (short*)qhatR;                       // [H][S][576] bf16 (37.7 MB)
  short* wkvbb  = qhatb + (long)H_N * S_LEN * D_QK;    // 4096x512
  short* oprojb = wkvbb + (long)4096 * 512;            // [S,2048] bf16
  short* wob    = oprojb + (long)2048 * 2048;          // 2048x2048

  // region C aliases: pre-flash bf16 scratch (dead by step 8)
  short* xb   = (short*)obufR;                         // 2048x2048 (dead after 2)
  short* wcat = xb + (long)2048 * 2048;                // [3712][2048] wq|wkv_a|0
  short* wukT = wcat + (long)3712 * 2048;              // 16x512x128 (dead after 6)

  // 1) all input casts in one dispatch
  cast_all<<<dim3(CSEG5 / 256), 256, 0, stream>>>(
      x, wq, wkv_a, wkv_b, wo, xb, wcat, wkvbb, wob);

  // 2+3) merged: {qbufb bf16 | kvpad f32} = x @ [wq; wkv_a_pad]^T (928 blk)
  gemm_qkv_m64<<<dim3(3712 / 128, 2048 / 64, 1), 256, 0, stream>>>(
      xb, wcat, qbufb, kvpad);

  // 4) RMSNorm + RoPE
  prep_kernel<<<dim3(S_LEN), 64, 0, stream>>>(kvpad, qbufb, qhatb, cosp, sinp, normw);

  // 5) build wukT
  transpose_wuk<<<dim3(4, 16, 16), 256, 0, stream>>>(wkv_b, wukT);

  // 6) qhatb[:, :512] = bf16(q_nope @ w_uk)  (MT=64: 2048 blocks)
  gemm_bf16_nt_m64<<<dim3(512 / 128, 2048 / 64, 16), 256, 0, stream>>>(
      qbufb, wukT, qhatb, 128, 3072, 128, 576,
      192L, 512L * 128, (long)S_LEN * D_QK, 1);

  // 7) K/V layout transforms
  transpose_v<<<dim3(16, 64), 256, 0, stream>>>(kbf, kvt);
  build_ktt<<<dim3(128), 256, 0, stream>>>(kbf, ktt);
  build_vtt<<<dim3(64), 256, 0, stream>>>(kvt, vtt);

  // 8) flash attention + fused oproj GEMM -> oprojb bf16 directly
  flash_reg<<<dim3(512), 512, 0, stream>>>(qhatb, ktt, vtt, wkvbb, oprojb);

  // 11) out = oprojb @ wo^T  (MT=64, verified r11)
  gemm_bf16_nt_m64<<<dim3(2048 / 128, 2048 / 64, 1), 256, 0, stream>>>(
      oprojb, wob, out, 2048, 2048, 2048, 2048, 0, 0, 0, 0);
}

// Round 14
// 397.750 us; speedup vs baseline: 1.0400x; 1.0400x over previous
//
#include <hip/hip_runtime.h>
#include <hip/hip_bf16.h>
#include <math.h>

// Problem constants
#define S_LEN 2048
#define DIM   2048
#define H_N   16
#define NOPE  128
#define ROPE  64
#define VD    128
#define LORA  512
#define D_QK  576
#define SCALE_F 0.07216878364870323f   // 192^-0.5
#define EPS_F 1e-6f
#define KVF 640                        // padded kv row (f32 elems)
#define KVS 1280                       // padded kv row (shorts)

typedef short short8 __attribute__((ext_vector_type(8)));
typedef short short4v __attribute__((ext_vector_type(4)));
typedef float floatx4 __attribute__((ext_vector_type(4)));

static __device__ inline unsigned short f2bf_bits(float f) {
  union { __hip_bfloat16 h; unsigned short u; } cv;
  cv.h = __float2bfloat16(f);
  return cv.u;
}

static __device__ inline float bf2f(unsigned short b) {
  union { unsigned u; float f; } cv;
  cv.u = (unsigned)b << 16;
  return cv.f;
}

// global_load_lds: LDS destination must be WAVE-UNIFORM; lane's 16B lands at
// base + lane*16 automatically.
static __device__ inline void gload_lds16(const short* gptr, short* lds_base_uniform) {
  __builtin_amdgcn_global_load_lds(
      (const __attribute__((address_space(1))) void*)gptr,
      (__attribute__((address_space(3))) void*)lds_base_uniform, 16, 0, 0);
}

static __device__ inline void cast8(const float* __restrict__ src,
                                    short* __restrict__ dst, int i) {
  float4 a = ((const float4*)src)[2 * i];
  float4 b = ((const float4*)src)[2 * i + 1];
  uint4 o;
  o.x = (unsigned)f2bf_bits(a.x) | ((unsigned)f2bf_bits(a.y) << 16);
  o.y = (unsigned)f2bf_bits(a.z) | ((unsigned)f2bf_bits(a.w) << 16);
  o.z = (unsigned)f2bf_bits(b.x) | ((unsigned)f2bf_bits(b.y) << 16);
  o.w = (unsigned)f2bf_bits(b.z) | ((unsigned)f2bf_bits(b.w) << 16);
  ((uint4*)dst)[i] = o;
}

// ---------------------------------------------------------------------------
// One kernel for ALL input casts (depend only on kernel inputs):
// x->xb, wq->wcat[0:3072), wkv_a->wcat[3072:3648), zero wcat[3648:3712),
// wkv_b->wkvbb, wo->wob.  Replaces 6 dispatches.
// ---------------------------------------------------------------------------
#define CSEG0 524288              // x        2048x2048/8
#define CSEG1 (CSEG0 + 786432)    // wq       3072x2048/8
#define CSEG2 (CSEG1 + 147456)    // wkv_a    576x2048/8
#define CSEG3 (CSEG2 + 16384)     // zero     64x2048/8
#define CSEG4 (CSEG3 + 262144)    // wkv_b    4096x512/8
#define CSEG5 (CSEG4 + 524288)    // wo       2048x2048/8  -> total 2260992
__global__ __launch_bounds__(256) void cast_all(
    const float* __restrict__ x, const float* __restrict__ wq,
    const float* __restrict__ wkv_a, const float* __restrict__ wkv_b,
    const float* __restrict__ wo, short* __restrict__ xb,
    short* __restrict__ wcat, short* __restrict__ wkvbb,
    short* __restrict__ wob) {
  int i = blockIdx.x * 256 + threadIdx.x;
  if (i < CSEG0) {
    cast8(x, xb, i);
  } else if (i < CSEG1) {
    cast8(wq, wcat, i - CSEG0);
  } else if (i < CSEG2) {
    cast8(wkv_a, wcat + 3072 * 2048, i - CSEG1);
  } else if (i < CSEG3) {
    ((uint4*)(wcat + 3072 * 2048 + 576 * 2048))[i - CSEG2] = (uint4){0u, 0u, 0u, 0u};
  } else if (i < CSEG4) {
    cast8(wkv_b, wkvbb, i - CSEG3);
  } else if (i < CSEG5) {
    cast8(wo, wob, i - CSEG4);
  }
}

// ---------------------------------------------------------------------------
// wukT[h][c][d] = wkv_b[h*256 + d][c]  (f32 in, bf16 out), c<512, d<128
// ---------------------------------------------------------------------------
__global__ __launch_bounds__(256) void transpose_wuk(
    const float* __restrict__ wkvb, short* __restrict__ wukT) {
  __shared__ float tile[32][33];
  const int h = blockIdx.z, c0 = blockIdx.y * 32, d0 = blockIdx.x * 32;
  const int t = threadIdx.x;
  const int r = t >> 3, c4 = (t & 7) * 4;
  float4 v = *(const float4*)(wkvb + ((long)h * 256 + d0 + r) * 512 + c0 + c4);
  tile[r][c4 + 0] = v.x; tile[r][c4 + 1] = v.y;
  tile[r][c4 + 2] = v.z; tile[r][c4 + 3] = v.w;
  __syncthreads();
  uint2 o;
  o.x = (unsigned)f2bf_bits(tile[c4 + 0][r]) | ((unsigned)f2bf_bits(tile[c4 + 1][r]) << 16);
  o.y = (unsigned)f2bf_bits(tile[c4 + 2][r]) | ((unsigned)f2bf_bits(tile[c4 + 3][r]) << 16);
  *(uint2*)(wukT + ((long)h * 512 + c0 + r) * 128 + d0 + c4) = o;
}

// ---------------------------------------------------------------------------
// MT=64 bf16 MFMA NT GEMM (verified round 11): acc 2x4, half-height A tile.
// ---------------------------------------------------------------------------
__global__ __launch_bounds__(256) void gemm_bf16_nt_m64(
    const short* __restrict__ A, const short* __restrict__ B, void* __restrict__ Cv,
    int K, int lda, int ldb, int ldc, long aB, long bB, long cB, int bf16out) {
  A += (long)blockIdx.z * aB;
  B += (long)blockIdx.z * bB;
  const int m0 = blockIdx.y * 64, n0 = blockIdx.x * 128;
  __shared__ short As[2][64 * 32];
  __shared__ short Bs[2][128 * 32];
  const int tid = threadIdx.x, w = tid >> 6, lane = tid & 63;
  const int ln = lane & 15, g = lane >> 4;
  const int mw = (w & 1) * 32, nw = (w >> 1) * 64;
  floatx4 acc[2][4];
#pragma unroll
  for (int i = 0; i < 2; ++i)
#pragma unroll
    for (int j = 0; j < 4; ++j) acc[i][j] = (floatx4){0.f, 0.f, 0.f, 0.f};

#define GEMM_STAGE64(k0_, b_)                                                  \
  {                                                                            \
    {                                                                          \
      const int bc = w * 64;                                                   \
      const int c = bc + lane;                                                 \
      const int row = c >> 2, quar = c & 3;                                    \
      gload_lds16(A + (long)(m0 + row) * lda + (k0_) + quar * 8, As[b_] + bc * 8); \
    }                                                                          \
    _Pragma("unroll")                                                          \
    for (int i = 0; i < 2; ++i) {                                              \
      const int bc = (i * 4 + w) * 64;                                         \
      const int c = bc + lane;                                                 \
      const int row = c >> 2, quar = c & 3;                                    \
      gload_lds16(B + (long)(n0 + row) * ldb + (k0_) + quar * 8, Bs[b_] + bc * 8); \
    }                                                                          \
  }

  GEMM_STAGE64(0, 0);
  __syncthreads();
  const int nk = K >> 5;
  for (int kt = 0; kt < nk; ++kt) {
    const int cb = kt & 1;
    if (kt + 1 < nk) GEMM_STAGE64((kt + 1) << 5, cb ^ 1);
    short8 af[2], bf_[4];
#pragma unroll
    for (int mi = 0; mi < 2; ++mi)
      af[mi] = *(const short8*)(As[cb] + (mw + mi * 16 + ln) * 32 + g * 8);
#pragma unroll
    for (int ni = 0; ni < 4; ++ni)
      bf_[ni] = *(const short8*)(Bs[cb] + (nw + ni * 16 + ln) * 32 + g * 8);
#pragma unroll
    for (int mi = 0; mi < 2; ++mi)
#pragma unroll
      for (int ni = 0; ni < 4; ++ni)
        acc[mi][ni] = __builtin_amdgcn_mfma_f32_16x16x32_bf16(af[mi], bf_[ni], acc[mi][ni], 0, 0, 0);
    __syncthreads();
  }
#undef GEMM_STAGE64
  if (bf16out) {
    short* Cs = (short*)Cv + (long)blockIdx.z * cB;
#pragma unroll
    for (int mi = 0; mi < 2; ++mi)
#pragma unroll
      for (int ni = 0; ni < 4; ++ni)
#pragma unroll
        for (int r = 0; r < 4; ++r)
          Cs[(long)(m0 + mw + mi * 16 + g * 4 + r) * ldc + n0 + nw + ni * 16 + ln] =
              (short)f2bf_bits(acc[mi][ni][r]);
  } else {
    float* C = (float*)Cv + (long)blockIdx.z * cB;
#pragma unroll
    for (int mi = 0; mi < 2; ++mi)
#pragma unroll
      for (int ni = 0; ni < 4; ++ni)
#pragma unroll
        for (int r = 0; r < 4; ++r)
          C[(long)(m0 + mw + mi * 16 + g * 4 + r) * ldc + n0 + nw + ni * 16 + ln] = acc[mi][ni][r];
  }
}

// ---------------------------------------------------------------------------
// Merged step-2/3 GEMM (verified r12): B = wcat [3712][2048] = [wq;wkv_a;0].
// n0<3072 -> bf16 qbuf (ldc 3072); n0>=3072 -> f32 kvpad (ldc KVF).
// ---------------------------------------------------------------------------
__global__ __launch_bounds__(256) void gemm_qkv_m64(
    const short* __restrict__ A, const short* __restrict__ B,
    short* __restrict__ Cq, float* __restrict__ Ckv) {
  const int m0 = blockIdx.y * 64, n0 = blockIdx.x * 128;
  __shared__ short As[2][64 * 32];
  __shared__ short Bs[2][128 * 32];
  const int tid = threadIdx.x, w = tid >> 6, lane = tid & 63;
  const int ln = lane & 15, g = lane >> 4;
  const int mw = (w & 1) * 32, nw = (w >> 1) * 64;
  floatx4 acc[2][4];
#pragma unroll
  for (int i = 0; i < 2; ++i)
#pragma unroll
    for (int j = 0; j < 4; ++j) acc[i][j] = (floatx4){0.f, 0.f, 0.f, 0.f};

#define QKV_STAGE(k0_, b_)                                                     \
  {                                                                            \
    {                                                                          \
      const int bc = w * 64;                                                   \
      const int c = bc + lane;                                                 \
      const int row = c >> 2, quar = c & 3;                                    \
      gload_lds16(A + (long)(m0 + row) * 2048 + (k0_) + quar * 8, As[b_] + bc * 8); \
    }                                                                          \
    _Pragma("unroll")                                                          \
    for (int i = 0; i < 2; ++i) {                                              \
      const int bc = (i * 4 + w) * 64;                                         \
      const int c = bc + lane;                                                 \
      const int row = c >> 2, quar = c & 3;                                    \
      gload_lds16(B + (long)(n0 + row) * 2048 + (k0_) + quar * 8, Bs[b_] + bc * 8); \
    }                                                                          \
  }

  QKV_STAGE(0, 0);
  __syncthreads();
  for (int kt = 0; kt < 64; ++kt) {
    const int cb = kt & 1;
    if (kt + 1 < 64) QKV_STAGE((kt + 1) << 5, cb ^ 1);
    short8 af[2], bf_[4];
#pragma unroll
    for (int mi = 0; mi < 2; ++mi)
      af[mi] = *(const short8*)(As[cb] + (mw + mi * 16 + ln) * 32 + g * 8);
#pragma unroll
    for (int ni = 0; ni < 4; ++ni)
      bf_[ni] = *(const short8*)(Bs[cb] + (nw + ni * 16 + ln) * 32 + g * 8);
#pragma unroll
    for (int mi = 0; mi < 2; ++mi)
#pragma unroll
      for (int ni = 0; ni < 4; ++ni)
        acc[mi][ni] = __builtin_amdgcn_mfma_f32_16x16x32_bf16(af[mi], bf_[ni], acc[mi][ni], 0, 0, 0);
    __syncthreads();
  }
#undef QKV_STAGE
  if (n0 < 3072) {
#pragma unroll
    for (int mi = 0; mi < 2; ++mi)
#pragma unroll
      for (int ni = 0; ni < 4; ++ni)
#pragma unroll
        for (int r = 0; r < 4; ++r)
          Cq[(long)(m0 + mw + mi * 16 + g * 4 + r) * 3072 + n0 + nw + ni * 16 + ln] =
              (short)f2bf_bits(acc[mi][ni][r]);
  } else {
#pragma unroll
    for (int mi = 0; mi < 2; ++mi)
#pragma unroll
      for (int ni = 0; ni < 4; ++ni)
#pragma unroll
        for (int r = 0; r < 4; ++r)
          Ckv[(long)(m0 + mw + mi * 16 + g * 4 + r) * KVF + (n0 - 3072) + nw + ni * 16 + ln] =
              acc[mi][ni][r];
  }
}

// ---------------------------------------------------------------------------
// prep: RMSNorm + RoPE on kv rows (f32 stride KVF) -> bf16 in place (short
// stride KVS, first 576 valid); q_pe RoPE from bf16 qbufb -> bf16 qhat tail
// ---------------------------------------------------------------------------
__global__ __launch_bounds__(64) void prep_kernel(
    float* kv, const short* __restrict__ qbufb, short* __restrict__ qhatb,
    const float* __restrict__ cosp, const float* __restrict__ sinp,
    const float* __restrict__ normw) {
  const int s = blockIdx.x;
  const int l = threadIdx.x;
  float* row = kv + (long)s * KVF;
  short* krow = (short*)kv + (long)s * KVS;

  float4 v0 = *(const float4*)(row + l * 8);
  float4 v1 = *(const float4*)(row + l * 8 + 4);
  float rx0 = 0.f, rx1 = 0.f, rc = 0.f, rs = 0.f;
  if (l < 32) {
    rc = cosp[s * 32 + l];
    rs = sinp[s * 32 + l];
    rx0 = row[512 + 2 * l];
    rx1 = row[512 + 2 * l + 1];
  }
  float4 w0 = *(const float4*)(normw + l * 8);
  float4 w1 = *(const float4*)(normw + l * 8 + 4);

  float ss = v0.x * v0.x + v0.y * v0.y + v0.z * v0.z + v0.w * v0.w +
             v1.x * v1.x + v1.y * v1.y + v1.z * v1.z + v1.w * v1.w;
#pragma unroll
  for (int off = 32; off; off >>= 1) ss += __shfl_xor(ss, off, 64);
  const float scale = rsqrtf(ss * (1.0f / (float)LORA) + EPS_F);
  v0.x *= scale * w0.x; v0.y *= scale * w0.y; v0.z *= scale * w0.z; v0.w *= scale * w0.w;
  v1.x *= scale * w1.x; v1.y *= scale * w1.y; v1.z *= scale * w1.z; v1.w *= scale * w1.w;

  uint4 pk;
  pk.x = (unsigned)f2bf_bits(v0.x) | ((unsigned)f2bf_bits(v0.y) << 16);
  pk.y = (unsigned)f2bf_bits(v0.z) | ((unsigned)f2bf_bits(v0.w) << 16);
  pk.z = (unsigned)f2bf_bits(v1.x) | ((unsigned)f2bf_bits(v1.y) << 16);
  pk.w = (unsigned)f2bf_bits(v1.z) | ((unsigned)f2bf_bits(v1.w) << 16);
  *(uint4*)(krow + l * 8) = pk;

  if (l < 32) {
    const float y0 = rx0 * rc - rx1 * rs;
    const float y1 = rx0 * rs + rx1 * rc;
    unsigned pr = (unsigned)f2bf_bits(y0) | ((unsigned)f2bf_bits(y1) << 16);
    *(unsigned*)(krow + 512 + 2 * l) = pr;
  }

#pragma unroll
  for (int it = 0; it < 8; ++it) {
    const int p = it * 64 + l;
    const int h = p >> 5;
    const int i = p & 31;
    const float c = cosp[s * 32 + i];
    const float sn = sinp[s * 32 + i];
    const short* qp = qbufb + (long)s * 3072 + h * 192 + NOPE;
    const unsigned uq = *(const unsigned*)(qp + 2 * i);
    const float x0 = bf2f((unsigned short)uq);
    const float x1 = bf2f((unsigned short)(uq >> 16));
    const float y0 = x0 * c - x1 * sn;
    const float y1 = x0 * sn + x1 * c;
    short* dst = qhatb + ((long)h * S_LEN + s) * D_QK + 512;
    *(unsigned*)(dst + 2 * i) = (unsigned)f2bf_bits(y0) | ((unsigned)f2bf_bits(y1) << 16);
  }
}

// ---------------------------------------------------------------------------
// Fragment-major K: ktt[kt][c][lane][8]
// ---------------------------------------------------------------------------
__global__ __launch_bounds__(256) void build_ktt(
    const short* __restrict__ kbf, short* __restrict__ ktt) {
  const int kt = blockIdx.x;                     // 0..127
  for (int idx = threadIdx.x; idx < 18 * 64; idx += 256) {
    const int c = idx >> 6, l = idx & 63;
    const int ln = l & 15, g = l >> 4;
    uint4 v = *(const uint4*)(kbf + (long)(kt * 16 + ln) * KVS + c * 32 + g * 8);
    *(uint4*)(ktt + ((long)(kt * 18 + c) * 64 + l) * 8) = v;
  }
}

// ---------------------------------------------------------------------------
// Fragment-major V^T DIRECT from kbf (replaces transpose_v + build_vtt and
// deletes the 2MB kvt intermediate): one 32(s) x 32(d) tile per block.
// vtt[kt][nt][l][j] = V^T[d=nt*16+ln][s=kt*32+g*8+j] = kbf[s][d].
// Block (a, kt): d0 = a*32 covers nt in {2a, 2a+1}; s0 = kt*32.
// ---------------------------------------------------------------------------
__global__ __launch_bounds__(256) void build_vtt_direct(
    const short* __restrict__ kbf, short* __restrict__ vtt) {
  __shared__ short tile[32][36];
  const int a = blockIdx.x;            // d-tile 0..15
  const int kt = blockIdx.y;           // s-tile 0..63
  const int d0 = a * 32, s0 = kt * 32;
  const int t = threadIdx.x;
  // load: row r = s_loc, cols c4..c4+3 = d_loc
  {
    const int r = t >> 3, c4 = (t & 7) * 4;
    uint2 v = *(const uint2*)(kbf + (long)(s0 + r) * KVS + d0 + c4);
    *(uint2*)(&tile[r][c4]) = v;
  }
  __syncthreads();
  // write: b = nt&1, l = lane, jh = j-half; 4 shorts per thread
  const int b = t >> 7;                // 0..1
  const int l = t & 63;
  const int jh = (t >> 6) & 1;         // 0..1
  const int ln = l & 15, g = l >> 4;
  uint2 o;
  {
    const int col = b * 16 + ln;
    const int r0 = g * 8 + jh * 4;
    o.x = (unsigned)(unsigned short)tile[r0 + 0][col] |
          ((unsigned)(unsigned short)tile[r0 + 1][col] << 16);
    o.y = (unsigned)(unsigned short)tile[r0 + 2][col] |
          ((unsigned)(unsigned short)tile[r0 + 3][col] << 16);
  }
  *(uint2*)(vtt + ((long)(kt * 32 + 2 * a + b) * 64 + l) * 8 + jh * 4) = o;
}

// ---------------------------------------------------------------------------
// Flash v13 (UNCHANGED; verified 160-163 us): block = 512 thr = 8 waves =
// 2 heads x 2 dh x 2 q-subtiles; K+V LDS staged, dh-split QK, P exchange
// via LDS, one barrier per 32-key pair.
// ---------------------------------------------------------------------------
__global__ __launch_bounds__(512, 2) void flash_reg(
    const short* __restrict__ qhat,   // [H][S][576] bf16
    const short* __restrict__ ktt,    // [128][18][64][8] bf16 frag-major K
    const short* __restrict__ vtt,    // [64][32][64][8] bf16 frag-major V^T
    short* __restrict__ obuf) {       // [H][S][512] bf16
  const int bid = blockIdx.x;         // 0..511
  const int hp = bid & 7;             // head pair
  const int v = bid >> 3;             // 0..63
  const int vi = v & 31, vj = v >> 5;
  const int qt2 = (vj == 0) ? 63 - vi : vi;   // 32-query tile, longest first
  const int q0 = qt2 * 32;
  const int tid = threadIdx.x;
  const int w = tid >> 6;             // wave 0..7
  const int lane = tid & 63;
  const int ln = lane & 15, g = lane >> 4;
  const int hh = w & 1;               // head parity
  const int dh = (w >> 1) & 1;        // key-half for QK; d-half for PV
  const int qt = w >> 2;              // q-subtile (16 queries)
  const int h = hp * 2 + hh;
  const int qrow = q0 + qt * 16 + ln;
  const int qlim = qrow;

  __shared__ short Kt[2][36 * 512];              // 72 KB K pairs (dbuf)
  __shared__ short Vt[2][32 * 512];              // 64 KB V pairs (dbuf)
  __shared__ __align__(16) short Pl[2][2][2][16][40]; // [par][hh][qt][q][keypad]
  __shared__ float Ls[8][16];                    // cross-dh lsum exchange

  // Q B-frags: n = ln (query), k = g*8+j
  short8 qfr[18];
  {
    const short* qr = qhat + ((long)h * S_LEN + qrow) * D_QK;
#pragma unroll
    for (int c = 0; c < 18; ++c)
      qfr[c] = *(const short8*)(qr + c * 32 + g * 8);
  }

  floatx4 oacc[16];
#pragma unroll
  for (int nt = 0; nt < 16; ++nt) oacc[nt] = (floatx4){0.f, 0.f, 0.f, 0.f};
  float lsum = 0.f;

  const int npairs = qt2 + 1;         // 32-key steps

#define FL_STAGEK(pair_, b_)                                                   \
  {                                                                            \
    const short* ks_ = ktt + (long)(pair_) * (36 * 512);                       \
    _Pragma("unroll")                                                          \
    for (int i = 0; i < 5; ++i) {                                              \
      const int grp = i * 8 + w;                                               \
      if (grp < 36)                                                            \
        gload_lds16(ks_ + (long)(grp * 64 + lane) * 8, Kt[b_] + grp * 512);    \
    }                                                                          \
  }

#define FL_STAGEV(pair_, b_)                                                   \
  {                                                                            \
    const short* vs_ = vtt + (long)(pair_) * (32 * 512);                       \
    _Pragma("unroll")                                                          \
    for (int i = 0; i < 4; ++i) {                                              \
      const int grp = i * 8 + w;                                               \
      gload_lds16(vs_ + (long)(grp * 64 + lane) * 8, Vt[b_] + grp * 512);      \
    }                                                                          \
  }

#define FL_PV(par_)                                                            \
  {                                                                            \
    const short8 pb8 = *(const short8*)(&Pl[par_][hh][qt][ln][g * 8]);         \
    const short* vb_ = Vt[par_] + dh * (16 * 512);                             \
    _Pragma("unroll")                                                          \
    for (int half = 0; half < 2; ++half) {                                     \
      short8 va[8];                                                            \
      _Pragma("unroll")                                                        \
      for (int j = 0; j < 8; ++j)                                              \
        va[j] = *(const short8*)(vb_ + (half * 8 + j) * 512 + lane * 8);       \
      __builtin_amdgcn_s_setprio(1);                                           \
      _Pragma("unroll")                                                        \
      for (int j = 0; j < 8; ++j)                                              \
        oacc[half * 8 + j] = __builtin_amdgcn_mfma_f32_16x16x32_bf16(          \
            va[j], pb8, oacc[half * 8 + j], 0, 0, 0);                          \
      __builtin_amdgcn_s_setprio(0);                                           \
    }                                                                          \
  }

  FL_STAGEK(0, 0);
  __syncthreads();

  for (int p = 0; p < npairs; ++p) {
    const int cb = p & 1;
    if (p + 1 < npairs) FL_STAGEK(p + 1, cb ^ 1);
    FL_STAGEV(p, cb);
    // ---- QK^T on this wave's 16-key half (dh selects half of pair p) ----
    const short* kb = Kt[cb] + dh * (18 * 512);
    floatx4 s0 = (floatx4){0.f, 0.f, 0.f, 0.f};
    floatx4 s1 = (floatx4){0.f, 0.f, 0.f, 0.f};
    __builtin_amdgcn_s_setprio(1);
#pragma unroll
    for (int c = 0; c < 18; c += 2) {
      short8 k0 = *(const short8*)(kb + (c * 64 + lane) * 8);
      short8 k1 = *(const short8*)(kb + ((c + 1) * 64 + lane) * 8);
      s0 = __builtin_amdgcn_mfma_f32_16x16x32_bf16(k0, qfr[c], s0, 0, 0, 0);
      s1 = __builtin_amdgcn_mfma_f32_16x16x32_bf16(k1, qfr[c + 1], s1, 0, 0, 0);
    }
    __builtin_amdgcn_s_setprio(0);
    // ---- softmax on 4 scores: keys p*32 + dh*16 + 4g + r ----
    short4v p4;
    float psum = 0.f;
#pragma unroll
    for (int r = 0; r < 4; ++r) {
      const int ki = p * 32 + dh * 16 + g * 4 + r;
      float sc = fminf(fmaxf((s0[r] + s1[r]) * SCALE_F, -30.f), 30.f);
      float pv_ = (ki <= qlim) ? __expf(sc) : 0.f;
      psum += pv_;
      p4[r] = (short)f2bf_bits(pv_);
    }
    lsum += psum;
    // ---- publish P half-tile ----
    union { short4v s; unsigned long long u; } upk;
    upk.s = p4;
    *(unsigned long long*)(&Pl[cb][hh][qt][ln][dh * 16 + g * 4]) = upk.u;
    // ---- PV for pair p-1 (P and V both at parity cb^1, fenced) ----
    if (p > 0) FL_PV(cb ^ 1);
    __syncthreads();
  }
  // final pending PV (parity of last iteration)
  FL_PV((npairs - 1) & 1);
#undef FL_PV
#undef FL_STAGEV
#undef FL_STAGEK

  // denominator: reduce over g within wave, then across the dh pair (w^2)
  lsum += __shfl_xor(lsum, 16, 64);
  lsum += __shfl_xor(lsum, 32, 64);
  if (g == 0) Ls[w][ln] = lsum;
  __syncthreads();
  lsum += Ls[w ^ 2][ln];
  const float inv = 1.0f / fmaxf(lsum, 1e-30f);

  // O^T tile -> bf16: d = dh*256 + nt*16 + g*4 + r, query = qrow
  short* orow = obuf + ((long)h * S_LEN + qrow) * 512 + dh * 256 + g * 4;
#pragma unroll
  for (int nt = 0; nt < 16; ++nt) {
    unsigned lo = (unsigned)f2bf_bits(oacc[nt][0] * inv) | ((unsigned)f2bf_bits(oacc[nt][1] * inv) << 16);
    unsigned hi = (unsigned)f2bf_bits(oacc[nt][2] * inv) | ((unsigned)f2bf_bits(oacc[nt][3] * inv) << 16);
    unsigned long long st = (unsigned long long)lo | ((unsigned long long)hi << 32);
    *(unsigned long long*)(orow + nt * 16) = st;
  }
}

// ---------------------------------------------------------------------------
// Host launch
// ---------------------------------------------------------------------------
extern "C" void kernel_launch(void* const* d_in, const int* in_sizes, int n_in,
                              void* d_out, int out_size, void* d_ws, size_t ws_size,
                              hipStream_t stream) {
  (void)in_sizes; (void)n_in; (void)out_size; (void)ws_size;
  const float* x      = (const float*)d_in[0];
  const float* cosp   = (const float*)d_in[1];
  const float* sinp   = (const float*)d_in[2];
  const float* wq     = (const float*)d_in[3];
  const float* wkv_a  = (const float*)d_in[4];
  const float* normw  = (const float*)d_in[5];
  const float* wkv_b  = (const float*)d_in[6];
  const float* wo     = (const float*)d_in[7];
  float* out = (float*)d_out;

  float* ws = (float*)d_ws;
  float* qbufR  = ws;                                  // region A: 25.2 MB
  float* kvold  = qbufR + (long)S_LEN * 3072;          // 4.7 MB (spare)
  float* qhatR  = kvold + (long)S_LEN * D_QK;          // region B: 75.5 MB
  float* obufR  = qhatR + (long)H_N * S_LEN * D_QK;    // region C: 67 MB
  float* oprojR = obufR + (long)H_N * S_LEN * LORA;    // region D: 16.8 MB

  // region D: padded kv [S, KVF] f32 -> bf16 in place
  float* kvpad = oprojR;
  short* kbf = (short*)kvpad;                          // bf16 rows stride KVS

  // region A aliases
  short* qbufb = (short*)qbufR;                        // [S,3072] bf16 (12.6 MB)
  short* kvt = qbufb + (long)S_LEN * 3072;             // (spare, kvt deleted)
  short* ktt = kvt + (long)512 * S_LEN;                // 2.36 MB frag-major K
  short* vtt = ktt + (long)128 * 18 * 64 * 8;          // 2 MB frag-major V^T

  // region B aliases
  short* qhatb  = (short*)qhatR;                       // [H][S][576] bf16 (37.7 MB)
  short* wkvbb  = qhatb + (long)H_N * S_LEN * D_QK;    // 4096x512
  short* oprojb = wkvbb + (long)4096 * 512;            // [S,2048] bf16
  short* wob    = oprojb + (long)2048 * 2048;          // 2048x2048

  // region C aliases: pre-flash bf16 scratch (dead by step 8), then obufb
  short* xb   = (short*)obufR;                         // 2048x2048 (dead after 2)
  short* wcat = xb + (long)2048 * 2048;                // [3712][2048] wq|wkv_a|0
  short* wukT = wcat + (long)3712 * 2048;              // 16x512x128 (dead after 6)
  short* obufb = (short*)obufR;                        // [H][S][512] bf16 (step 8+)

  // 1) all input casts in one dispatch
  cast_all<<<dim3(CSEG5 / 256), 256, 0, stream>>>(
      x, wq, wkv_a, wkv_b, wo, xb, wcat, wkvbb, wob);

  // 2+3) merged: {qbufb bf16 | kvpad f32} = x @ [wq; wkv_a_pad]^T (928 blk)
  gemm_qkv_m64<<<dim3(3712 / 128, 2048 / 64, 1), 256, 0, stream>>>(
      xb, wcat, qbufb, kvpad);

  // 4) RMSNorm + RoPE
  prep_kernel<<<dim3(S_LEN), 64, 0, stream>>>(kvpad, qbufb, qhatb, cosp, sinp, normw);

  // 5) build wukT
  transpose_wuk<<<dim3(4, 16, 16), 256, 0, stream>>>(wkv_b, wukT);

  // 6) qhatb[:, :512] = bf16(q_nope @ w_uk)  (MT=64: 2048 blocks)
  gemm_bf16_nt_m64<<<dim3(512 / 128, 2048 / 64, 16), 256, 0, stream>>>(
      qbufb, wukT, qhatb, 128, 3072, 128, 576,
      192L, 512L * 128, (long)S_LEN * D_QK, 1);

  // 7) K/V layout transforms (kvt intermediate deleted)
  build_ktt<<<dim3(128), 256, 0, stream>>>(kbf, ktt);
  build_vtt_direct<<<dim3(16, 64), 256, 0, stream>>>(kbf, vtt);

  // 8) flash attention -> obufb bf16  (unchanged v13)
  flash_reg<<<dim3(512), 512, 0, stream>>>(qhatb, ktt, vtt, obufb);

  // 10) oprojb = bf16(obufb @ w_uv^T)  (MT=64, verified r11)
  gemm_bf16_nt_m64<<<dim3(1, 2048 / 64, 16), 256, 0, stream>>>(
      obufb, wkvbb + 128L * 512, oprojb, 512, 512, 512, 2048,
      (long)S_LEN * 512, 256L * 512, 128L, 1);

  // 11) out = oprojb @ wo^T  (MT=64, verified r11)
  gemm_bf16_nt_m64<<<dim3(2048 / 128, 2048 / 64, 1), 256, 0, stream>>>(
      oprojb, wob, out, 2048, 2048, 2048, 2048, 0, 0, 0, 0);
}